// Round 11
// baseline (60.347 us; speedup 1.0000x reference)
//
#include <hip/hip_runtime.h>

#define NB 32
#define NN 2048
#define NC 16
#define ND 128
#define NH 128
#define TM 32
#define NBLK (NB * (NN / TM))   // 2048 blocks of 256 threads

typedef __bf16 bf16x8 __attribute__((ext_vector_type(8)));
typedef float f32x4 __attribute__((ext_vector_type(4)));
typedef float f32x2 __attribute__((ext_vector_type(2)));

__device__ __forceinline__ unsigned short f2bf(float f){
  unsigned u = __float_as_uint(f);
  u = (u + 0x7fffu + ((u >> 16) & 1u)) >> 16;   // RNE
  return (unsigned short)u;
}
__device__ __forceinline__ unsigned enc_f32(float x){
  unsigned u = __float_as_uint(x);
  return (u & 0x80000000u) ? ~u : (u | 0x80000000u);
}
__device__ __forceinline__ float dec_f32(unsigned u){
  return __uint_as_float((u & 0x80000000u) ? (u & 0x7fffffffu) : ~u);
}

// swizzled LDS tile helpers (XOR bank swizzle: byte ^= (row&7)<<4)
__device__ __forceinline__ void stq(unsigned char* base, int stride, int row, int koff, uint4 u){
  *(uint4*)(base + row * stride + (koff ^ ((row & 7) << 4))) = u;
}
__device__ __forceinline__ void st8(unsigned char* base, int stride, int row, int koff, const float* f){
  uint4 u;
  u.x = (unsigned)f2bf(f[0]) | ((unsigned)f2bf(f[1]) << 16);
  u.y = (unsigned)f2bf(f[2]) | ((unsigned)f2bf(f[3]) << 16);
  u.z = (unsigned)f2bf(f[4]) | ((unsigned)f2bf(f[5]) << 16);
  u.w = (unsigned)f2bf(f[6]) | ((unsigned)f2bf(f[7]) << 16);
  stq(base, stride, row, koff, u);
}
__device__ __forceinline__ uint4 ldq(const unsigned char* base, int stride, int row, int koff){
  return *(const uint4*)(base + row * stride + (koff ^ ((row & 7) << 4)));
}

// ws layout
#define OFF_POOLED 0
#define OFF_W1     16384
#define OFF_W2     114688
#define OFF_EMB    147456
#define WS_NEED_BF (OFF_EMB + (size_t)NB*NN*ND*2)

// ---- unified prep ----
// blocks [0,2048): nodeEmb f32 -> bf16, XCD-affine (chunk for batch b on b's XCD)
// blocks [2048,2072): W1 frags [cf][ks][lane]x16B ; pooled init
// blocks [2072,2080): W2 frags [cf][ks][lane]x16B
__global__ __launch_bounds__(256) void tbcnn_prep(
    const float* __restrict__ nodeEmb, const float* __restrict__ W1,
    const float* __restrict__ W2, unsigned* __restrict__ pooled,
    uint4* __restrict__ w1frag, uint4* __restrict__ w2frag,
    ushort* __restrict__ embBf, int doEmb)
{
  const int blk = blockIdx.x;
  const int t = threadIdx.x;
  if (blk < 2048){
    if (!doEmb) return;
    const int chk = ((blk & 7) << 8) | (blk >> 3);
    const float4* src = (const float4*)nodeEmb;
    #pragma unroll
    for (int it = 0; it < 4; ++it){
      const int i = chk * 1024 + it * 256 + t;
      float4 v = src[i];
      ushort4 o;
      o.x = f2bf(v.x); o.y = f2bf(v.y); o.z = f2bf(v.z); o.w = f2bf(v.w);
      *(ushort4*)(embBf + (size_t)i * 4) = o;
    }
  } else if (blk < 2072){
    const int tt = (blk - 2048) * 256 + t;        // 0..6143
    if (tt < NB * NH) pooled[tt] = 0u;            // enc-min (any real value wins)
    const int lane = tt & 63;
    const int rest = tt >> 6;                     // 0..95
    const int ks = rest % 12;
    const int cf = rest / 12;
    const int col = (cf >> 1) * 32 + (cf & 1) * 16 + (lane & 15);
    const int k0 = ks * 32 + (lane >> 4) * 8;
    unsigned ps[4];
    #pragma unroll
    for (int p = 0; p < 4; ++p){
      unsigned lo = f2bf(W1[(size_t)(k0 + 2*p) * NH + col]);
      unsigned hi = f2bf(W1[(size_t)(k0 + 2*p + 1) * NH + col]);
      ps[p] = lo | (hi << 16);
    }
    w1frag[tt] = make_uint4(ps[0], ps[1], ps[2], ps[3]);
  } else {
    const int tt = (blk - 2072) * 256 + t;        // 0..2047
    const int lane = tt & 63;
    const int rest = tt >> 6;
    const int ks = rest & 3;
    const int cf = rest >> 2;
    const int col = (cf >> 1) * 32 + (cf & 1) * 16 + (lane & 15);
    const int k0 = ks * 32 + (lane >> 4) * 8;
    unsigned ps[4];
    #pragma unroll
    for (int p = 0; p < 4; ++p){
      unsigned lo = f2bf(W2[(size_t)(k0 + 2*p) * NH + col]);
      unsigned hi = f2bf(W2[(size_t)(k0 + 2*p + 1) * NH + col]);
      ps[p] = lo | (hi << 16);
    }
    w2frag[tt] = make_uint4(ps[0], ps[1], ps[2], ps[3]);
  }
}

// per-lane dword (2 bf16 dims) of row idx: 64 lanes cover the full 256B row ->
// ONE wave instruction = 2 cache lines (minimum). This is the R11 coalescing fix.
#define GLD(idx) (*(const unsigned*)(embBf + (rowbase + (unsigned)(idx)) * ND + (lane << 1)))

// process child k (weights wave-uniform; x = 2 dims from staged dword)
#define PRC(k, idx, creg) { \
  const float mk  = ((idx) > 0) ? 1.0f : 0.0f; \
  const float wrc = one_sib ? (0.5f * mk) : (mk * (float)(k) * rdiv); \
  const float wlc = (1.0f - wrc) * mk; \
  f32x2 x_; \
  x_[0] = __uint_as_float((creg) << 16); \
  x_[1] = __uint_as_float((creg) & 0xffff0000u); \
  aR += (f32x2){wrc, wrc} * x_; \
  aL += (f32x2){wlc, wlc} * x_; }

// ---- main: wave-per-node coalesced gather + wf (LDS) + MFMA + atomicMax ----
// (256,2): 256-VGPR cap; never force occupancy (R2/R4: <64 VGPR -> 300MB spill).
// No __threadfence / no exit ticket (R5/R9 lessons). Gather: each wave owns one
// node per pass; 17 coalesced dword-loads (self+16 children) issued before a
// sched_barrier(0); no fence between process(p) and issue(p+1) so passes overlap.
template<bool BF>
__global__ __launch_bounds__(256, 2) void tbcnn_main(
    const int* __restrict__ children, const float* __restrict__ nodeEmb,
    const ushort* __restrict__ embBf, const uint4* __restrict__ w1frag,
    unsigned* __restrict__ pooled)
{
  __shared__ __align__(16) unsigned char wf_raw[TM * 768];   // 24 KB
  // XCD-aware swizzle: 2048 blocks = 8 XCDs x 256; each XCD owns 4 batches
  const int j0 = ((blockIdx.x & 7) << 8) | (blockIdx.x >> 3);
  const int b = j0 >> 6;
  const int n0 = (j0 & 63) * TM;
  const int t = threadIdx.x;
  const int lane = t & 63;
  const int w = t >> 6;
  const size_t rowbase = (size_t)b * NN;

  if (BF){
    // ---- gather: wave w handles rows [w*8, w*8+8), one node per pass ----
    #pragma unroll
    for (int p = 0; p < 8; ++p){
      const int row = (w << 3) + p;
      const int gn = n0 + row;
      const int4* chp4 = (const int4*)(children + (rowbase + gn) * NC);
      const int4 v0 = chp4[0], v1 = chp4[1], v2 = chp4[2], v3 = chp4[3];
      int ns = (v0.x>0)+(v0.y>0)+(v0.z>0)+(v0.w>0)
             + (v1.x>0)+(v1.y>0)+(v1.z>0)+(v1.w>0)
             + (v2.x>0)+(v2.y>0)+(v2.z>0)+(v2.w>0)
             + (v3.x>0)+(v3.y>0)+(v3.z>0)+(v3.w>0);
      const float rdiv = 1.0f / (float)(((ns - 1) > 1) ? (ns - 1) : 1);
      const bool one_sib = (ns == 1);

      // issue all 17 coalesced loads (16-deep MLP, 2 lines per instruction)
      const unsigned sv = GLD(gn);
      const unsigned c0  = GLD(v0.x), c1  = GLD(v0.y), c2  = GLD(v0.z), c3  = GLD(v0.w);
      const unsigned c4  = GLD(v1.x), c5  = GLD(v1.y), c6  = GLD(v1.z), c7  = GLD(v1.w);
      const unsigned c8  = GLD(v2.x), c9  = GLD(v2.y), c10 = GLD(v2.z), c11 = GLD(v2.w);
      const unsigned c12 = GLD(v3.x), c13 = GLD(v3.y), c14 = GLD(v3.z), c15 = GLD(v3.w);
      __builtin_amdgcn_sched_barrier(0);

      f32x2 aR = (f32x2){0.f,0.f}, aL = (f32x2){0.f,0.f};
      PRC(0,  v0.x, c0)  PRC(1,  v0.y, c1)  PRC(2,  v0.z, c2)  PRC(3,  v0.w, c3)
      PRC(4,  v1.x, c4)  PRC(5,  v1.y, c5)  PRC(6,  v1.z, c6)  PRC(7,  v1.w, c7)
      PRC(8,  v2.x, c8)  PRC(9,  v2.y, c9)  PRC(10, v2.z, c10) PRC(11, v2.w, c11)
      PRC(12, v3.x, c12) PRC(13, v3.y, c13) PRC(14, v3.z, c14) PRC(15, v3.w, c15)

      // write wf row: self dword + packed R + packed L (swizzle uniform per wave)
      const unsigned uR = (unsigned)f2bf(aR[0]) | ((unsigned)f2bf(aR[1]) << 16);
      const unsigned uL = (unsigned)f2bf(aL[0]) | ((unsigned)f2bf(aL[1]) << 16);
      const int sw = (row & 7) << 4;
      unsigned char* rp = wf_raw + row * 768;
      *(unsigned*)(rp + (((lane << 2)      ) ^ sw)) = sv;
      *(unsigned*)(rp + ((256 + (lane << 2)) ^ sw)) = uR;
      *(unsigned*)(rp + ((512 + (lane << 2)) ^ sw)) = uL;
    }
  } else {
    // f32 fallback: R10 gather (8 thr/node, 16 dims)
    const int nloc = t >> 3;
    const int q = t & 7;
    const int d0 = q * 16;
    const int gn = n0 + nloc;
    const int4* chp4 = (const int4*)(children + (rowbase + gn) * NC);
    int ns = 0;
    #pragma unroll
    for (int c4 = 0; c4 < 4; ++c4){
      int4 v = chp4[c4];
      ns += (v.x > 0) + (v.y > 0) + (v.z > 0) + (v.w > 0);
    }
    const float rdiv = 1.0f / (float)(((ns - 1) > 1) ? (ns - 1) : 1);
    const bool one_sib = (ns == 1);
    const float* sp = nodeEmb + (rowbase + gn) * ND + d0;
    float sv[16];
    #pragma unroll
    for (int j = 0; j < 4; ++j){
      float4 s = *(const float4*)(sp + j * 4);
      sv[j*4+0]=s.x; sv[j*4+1]=s.y; sv[j*4+2]=s.z; sv[j*4+3]=s.w;
    }
    st8(wf_raw, 768, nloc, 2 * d0, sv);
    st8(wf_raw, 768, nloc, 2 * (d0 + 8), sv + 8);
    float aR[16], aL[16];
    #pragma unroll
    for (int i = 0; i < 16; ++i){ aR[i] = 0.0f; aL[i] = 0.0f; }
    #pragma unroll
    for (int c4 = 0; c4 < 4; ++c4){
      int4 v = chp4[c4];
      int cidx[4] = {v.x, v.y, v.z, v.w};
      #pragma unroll
      for (int jj = 0; jj < 4; ++jj){
        const int c = c4 * 4 + jj;
        const int idx = cidx[jj];
        const float mk  = (idx > 0) ? 1.0f : 0.0f;
        const float wrc = one_sib ? (0.5f * mk) : (mk * (float)c * rdiv);
        const float wlc = (1.0f - wrc) * mk;
        const float* cp = nodeEmb + (rowbase + idx) * ND + d0;
        #pragma unroll
        for (int j = 0; j < 4; ++j){
          float4 u = *(const float4*)(cp + j * 4);
          aR[j*4+0] += wrc * u.x; aL[j*4+0] += wlc * u.x;
          aR[j*4+1] += wrc * u.y; aL[j*4+1] += wlc * u.y;
          aR[j*4+2] += wrc * u.z; aL[j*4+2] += wlc * u.z;
          aR[j*4+3] += wrc * u.w; aL[j*4+3] += wlc * u.w;
        }
      }
    }
    st8(wf_raw, 768, nloc, 2 * (ND + d0),         aR);
    st8(wf_raw, 768, nloc, 2 * (ND + d0 + 8),     aR + 8);
    st8(wf_raw, 768, nloc, 2 * (2 * ND + d0),     aL);
    st8(wf_raw, 768, nloc, 2 * (2 * ND + d0 + 8), aL + 8);
  }
  __syncthreads();

  // ---- MFMA: 32 rows x 32 cols per wave, K=384; B frags streamed (L2-hot) ----
  {
    f32x4 acc[2][2];
    #pragma unroll
    for (int rf = 0; rf < 2; ++rf){
      acc[rf][0] = (f32x4){0.f, 0.f, 0.f, 0.f};
      acc[rf][1] = (f32x4){0.f, 0.f, 0.f, 0.f};
    }
    #pragma unroll 4
    for (int ks = 0; ks < 12; ++ks){
      bf16x8 B0 = __builtin_bit_cast(bf16x8, w1frag[((w * 2 + 0) * 12 + ks) * 64 + lane]);
      bf16x8 B1 = __builtin_bit_cast(bf16x8, w1frag[((w * 2 + 1) * 12 + ks) * 64 + lane]);
      const int koff = ks * 64 + ((lane >> 4) << 4);
      #pragma unroll
      for (int rf = 0; rf < 2; ++rf){
        const int row = rf * 16 + (lane & 15);
        bf16x8 a = __builtin_bit_cast(bf16x8, ldq(wf_raw, 768, row, koff));
        acc[rf][0] = __builtin_amdgcn_mfma_f32_16x16x32_bf16(a, B0, acc[rf][0], 0, 0, 0);
        acc[rf][1] = __builtin_amdgcn_mfma_f32_16x16x32_bf16(a, B1, acc[rf][1], 0, 0, 0);
      }
    }

    float m0 = -3.0e38f, m1 = -3.0e38f;
    #pragma unroll
    for (int rf = 0; rf < 2; ++rf)
      #pragma unroll
      for (int i = 0; i < 4; ++i){
        m0 = fmaxf(m0, acc[rf][0][i]);
        m1 = fmaxf(m1, acc[rf][1][i]);
      }
    m0 = fmaxf(m0, __shfl_xor(m0, 16, 64));
    m0 = fmaxf(m0, __shfl_xor(m0, 32, 64));
    m1 = fmaxf(m1, __shfl_xor(m1, 16, 64));
    m1 = fmaxf(m1, __shfl_xor(m1, 32, 64));
    if (lane < 16){
      atomicMax(pooled + b * NH + w * 32 + lane,      enc_f32(m0));
      atomicMax(pooled + b * NH + w * 32 + 16 + lane, enc_f32(m1));
    }
  }
}

// ---- final: h=tanh(pooled+b1) -> MFMA h@W2 -> tanh -> cosine(v1,v2) ----
__global__ __launch_bounds__(256) void tbcnn_final(
    const unsigned* __restrict__ pooled, const float* __restrict__ b1,
    const uint4* __restrict__ w2frag, const float* __restrict__ b2,
    float* __restrict__ out)
{
  __shared__ __align__(16) unsigned char hls[NB * 256];   // 32 x 128 bf16, swizzled
  __shared__ float os[NB * NH];
  const int t = threadIdx.x;
  const int lane = t & 63;
  const int w = t >> 6;

  {
    const int row = t >> 3;          // batch
    const int q = t & 7;
    const int d0 = q * 16;
    const unsigned* pp = pooled + row * NH + d0;
    const float* bp = b1 + d0;
    float hv[16];
    #pragma unroll
    for (int j = 0; j < 16; ++j) hv[j] = tanhf(dec_f32(pp[j]) + bp[j]);
    st8(hls, 256, row, 2 * d0, hv);
    st8(hls, 256, row, 2 * (d0 + 8), hv + 8);
  }
  __syncthreads();
  {
    f32x4 acc[2][2];
    #pragma unroll
    for (int rf = 0; rf < 2; ++rf){
      acc[rf][0] = (f32x4){0.f,0.f,0.f,0.f};
      acc[rf][1] = (f32x4){0.f,0.f,0.f,0.f};
    }
    #pragma unroll
    for (int ks = 0; ks < 4; ++ks){
      bf16x8 B0 = __builtin_bit_cast(bf16x8, w2frag[((w * 2 + 0) * 4 + ks) * 64 + lane]);
      bf16x8 B1 = __builtin_bit_cast(bf16x8, w2frag[((w * 2 + 1) * 4 + ks) * 64 + lane]);
      const int koff = ks * 64 + ((lane >> 4) << 4);
      #pragma unroll
      for (int rf = 0; rf < 2; ++rf){
        bf16x8 a = __builtin_bit_cast(bf16x8, ldq(hls, 256, rf * 16 + (lane & 15), koff));
        acc[rf][0] = __builtin_amdgcn_mfma_f32_16x16x32_bf16(a, B0, acc[rf][0], 0, 0, 0);
        acc[rf][1] = __builtin_amdgcn_mfma_f32_16x16x32_bf16(a, B1, acc[rf][1], 0, 0, 0);
      }
    }
    #pragma unroll
    for (int rf = 0; rf < 2; ++rf)
      #pragma unroll
      for (int cf = 0; cf < 2; ++cf){
        const int col = w * 32 + cf * 16 + (lane & 15);
        const float bias = b2[col];
        #pragma unroll
        for (int i = 0; i < 4; ++i){
          const int r = rf * 16 + (lane >> 4) * 4 + i;
          os[r * NH + col] = tanhf(acc[rf][cf][i] + bias);
        }
      }
  }
  __syncthreads();
  if (t < 16){
    float s12 = 0.f, s11 = 0.f, s22 = 0.f;
    #pragma unroll 4
    for (int d = 0; d < NH; ++d){
      float a = os[t * NH + d];
      float c = os[(t + 16) * NH + d];
      s12 += a * c; s11 += a * a; s22 += c * c;
    }
    float n1 = fmaxf(sqrtf(s11), 1e-8f);
    float n2 = fmaxf(sqrtf(s22), 1e-8f);
    out[t] = s12 / (n1 * n2);
  }
}

extern "C" void kernel_launch(void* const* d_in, const int* in_sizes, int n_in,
                              void* d_out, int out_size, void* d_ws, size_t ws_size,
                              hipStream_t stream)
{
  const int*   children = (const int*)d_in[0];
  const float* nodeEmb  = (const float*)d_in[1];
  const float* W1       = (const float*)d_in[2];
  const float* b1       = (const float*)d_in[3];
  const float* W2       = (const float*)d_in[4];
  const float* b2       = (const float*)d_in[5];
  float* out = (float*)d_out;

  unsigned* pooled = (unsigned*)((char*)d_ws + OFF_POOLED);
  uint4* w1frag    = (uint4*)((char*)d_ws + OFF_W1);
  uint4* w2frag    = (uint4*)((char*)d_ws + OFF_W2);
  ushort* embBf    = (ushort*)((char*)d_ws + OFF_EMB);

  const bool bf = (ws_size >= WS_NEED_BF);

  tbcnn_prep<<<2080, 256, 0, stream>>>(nodeEmb, W1, W2, pooled, w1frag, w2frag, embBf, bf ? 1 : 0);
  if (bf)
    tbcnn_main<true><<<NBLK, 256, 0, stream>>>(children, nodeEmb, embBf, w1frag, pooled);
  else
    tbcnn_main<false><<<NBLK, 256, 0, stream>>>(children, nodeEmb, embBf, w1frag, pooled);
  tbcnn_final<<<1, 256, 0, stream>>>(pooled, b1, w2frag, b2, out);
}

// Round 12
// 53.226 us; speedup vs baseline: 1.1338x; 1.1338x over previous
//
#include <hip/hip_runtime.h>

#define NB 32
#define NN 2048
#define NC 16
#define ND 128
#define NH 128
#define TM 32
#define NBLK (NB * (NN / TM))   // 2048 blocks of 256 threads

typedef __bf16 bf16x8 __attribute__((ext_vector_type(8)));
typedef float f32x4 __attribute__((ext_vector_type(4)));
typedef float f32x2 __attribute__((ext_vector_type(2)));

__device__ __forceinline__ unsigned short f2bf(float f){
  unsigned u = __float_as_uint(f);
  u = (u + 0x7fffu + ((u >> 16) & 1u)) >> 16;   // RNE
  return (unsigned short)u;
}
__device__ __forceinline__ unsigned enc_f32(float x){
  unsigned u = __float_as_uint(x);
  return (u & 0x80000000u) ? ~u : (u | 0x80000000u);
}
__device__ __forceinline__ float dec_f32(unsigned u){
  return __uint_as_float((u & 0x80000000u) ? (u & 0x7fffffffu) : ~u);
}

// swizzled LDS tile helpers (XOR bank swizzle: byte ^= (row&7)<<4)
__device__ __forceinline__ void stq(unsigned char* base, int stride, int row, int koff, uint4 u){
  *(uint4*)(base + row * stride + (koff ^ ((row & 7) << 4))) = u;
}
__device__ __forceinline__ void st8(unsigned char* base, int stride, int row, int koff, const float* f){
  uint4 u;
  u.x = (unsigned)f2bf(f[0]) | ((unsigned)f2bf(f[1]) << 16);
  u.y = (unsigned)f2bf(f[2]) | ((unsigned)f2bf(f[3]) << 16);
  u.z = (unsigned)f2bf(f[4]) | ((unsigned)f2bf(f[5]) << 16);
  u.w = (unsigned)f2bf(f[6]) | ((unsigned)f2bf(f[7]) << 16);
  stq(base, stride, row, koff, u);
}
__device__ __forceinline__ uint4 ldq(const unsigned char* base, int stride, int row, int koff){
  return *(const uint4*)(base + row * stride + (koff ^ ((row & 7) << 4)));
}

// ws layout
#define OFF_POOLED 0
#define OFF_W1     16384
#define OFF_W2     114688
#define OFF_EMB    147456
#define WS_NEED_BF (OFF_EMB + (size_t)NB*NN*ND*2)

// ---- unified prep ----
// blocks [0,2048): nodeEmb f32 -> bf16, XCD-affine (chunk for batch b on b's XCD)
// blocks [2048,2072): W1 frags [cf][ks][lane]x16B ; pooled init
// blocks [2072,2080): W2 frags [cf][ks][lane]x16B
__global__ __launch_bounds__(256) void tbcnn_prep(
    const float* __restrict__ nodeEmb, const float* __restrict__ W1,
    const float* __restrict__ W2, unsigned* __restrict__ pooled,
    uint4* __restrict__ w1frag, uint4* __restrict__ w2frag,
    ushort* __restrict__ embBf, int doEmb)
{
  const int blk = blockIdx.x;
  const int t = threadIdx.x;
  if (blk < 2048){
    if (!doEmb) return;
    const int chk = ((blk & 7) << 8) | (blk >> 3);
    const float4* src = (const float4*)nodeEmb;
    #pragma unroll
    for (int it = 0; it < 4; ++it){
      const int i = chk * 1024 + it * 256 + t;
      float4 v = src[i];
      ushort4 o;
      o.x = f2bf(v.x); o.y = f2bf(v.y); o.z = f2bf(v.z); o.w = f2bf(v.w);
      *(ushort4*)(embBf + (size_t)i * 4) = o;
    }
  } else if (blk < 2072){
    const int tt = (blk - 2048) * 256 + t;        // 0..6143
    if (tt < NB * NH) pooled[tt] = 0u;            // enc-min (any real value wins)
    const int lane = tt & 63;
    const int rest = tt >> 6;                     // 0..95
    const int ks = rest % 12;
    const int cf = rest / 12;
    const int col = (cf >> 1) * 32 + (cf & 1) * 16 + (lane & 15);
    const int k0 = ks * 32 + (lane >> 4) * 8;
    unsigned ps[4];
    #pragma unroll
    for (int p = 0; p < 4; ++p){
      unsigned lo = f2bf(W1[(size_t)(k0 + 2*p) * NH + col]);
      unsigned hi = f2bf(W1[(size_t)(k0 + 2*p + 1) * NH + col]);
      ps[p] = lo | (hi << 16);
    }
    w1frag[tt] = make_uint4(ps[0], ps[1], ps[2], ps[3]);
  } else {
    const int tt = (blk - 2072) * 256 + t;        // 0..2047
    const int lane = tt & 63;
    const int rest = tt >> 6;
    const int ks = rest & 3;
    const int cf = rest >> 2;
    const int col = (cf >> 1) * 32 + (cf & 1) * 16 + (lane & 15);
    const int k0 = ks * 32 + (lane >> 4) * 8;
    unsigned ps[4];
    #pragma unroll
    for (int p = 0; p < 4; ++p){
      unsigned lo = f2bf(W2[(size_t)(k0 + 2*p) * NH + col]);
      unsigned hi = f2bf(W2[(size_t)(k0 + 2*p + 1) * NH + col]);
      ps[p] = lo | (hi << 16);
    }
    w2frag[tt] = make_uint4(ps[0], ps[1], ps[2], ps[3]);
  }
}

// per-lane dword (2 bf16 dims) of row idx: 64 lanes cover the full 256B row ->
// ONE wave instruction = 2 cache lines (minimum). R11 coalescing fix.
#define GLD(idx) (*(const unsigned*)(embBf + (rowbase + (unsigned)(idx)) * ND + (lane << 1)))

// process child k: weights from LDS table (uniform broadcast b128), s/r accum.
#define PRCW(k, creg) { \
  const float4 wv = wlds[row][(k)]; \
  f32x2 x_; \
  x_[0] = __uint_as_float((creg) << 16); \
  x_[1] = __uint_as_float((creg) & 0xffff0000u); \
  sA += *(const f32x2*)&wv.x * x_; \
  rA += *(const f32x2*)&wv.z * x_; }

// ---- main: coalesced wave-per-node gather + LDS weight table + MFMA ----
// (256,2): 256-VGPR cap; never force occupancy (R2/R4: <64 VGPR -> 300MB spill).
// No __threadfence / no exit ticket (R5/R9). Weights precomputed lane-parallel
// into LDS (R11 post-mortem: wave-uniform recompute was ~half the gather VALU);
// l = s - r algebra removes the wl chain entirely.
template<bool BF>
__global__ __launch_bounds__(256, 2) void tbcnn_main(
    const int* __restrict__ children, const float* __restrict__ nodeEmb,
    const ushort* __restrict__ embBf, const uint4* __restrict__ w1frag,
    unsigned* __restrict__ pooled)
{
  __shared__ __align__(16) unsigned char wf_raw[TM * 768];   // 24 KB
  __shared__ __align__(16) float4 wlds[TM][NC];              // 8 KB {mk,mk,wr,wr}
  // XCD-aware swizzle: 2048 blocks = 8 XCDs x 256; each XCD owns 4 batches
  const int j0 = ((blockIdx.x & 7) << 8) | (blockIdx.x >> 3);
  const int b = j0 >> 6;
  const int n0 = (j0 & 63) * TM;
  const int t = threadIdx.x;
  const int lane = t & 63;
  const int w = t >> 6;
  const size_t rowbase = (size_t)b * NN;

  if (BF){
    // ---- phase A: lane-parallel weight table (wave-local: wave w's lanes
    // compute exactly the 8 nodes wave w will gather; no barrier needed) ----
    {
      const int node = t >> 3;            // == w*8 + (lane>>3)
      const int q = t & 7;
      const int gn = n0 + node;
      const int* chp = children + (rowbase + gn) * NC;
      const int i0 = chp[q * 2], i1 = chp[q * 2 + 1];
      const float m0 = (i0 > 0) ? 1.f : 0.f;
      const float m1 = (i1 > 0) ? 1.f : 0.f;
      float pns = m0 + m1;
      pns += __shfl_xor(pns, 1, 64);
      pns += __shfl_xor(pns, 2, 64);
      pns += __shfl_xor(pns, 4, 64);      // ns for this node, all 8 lanes
      const float rdiv = 1.0f / fmaxf(pns - 1.0f, 1.0f);
      const bool one_sib = (pns == 1.0f);
      const float w0 = one_sib ? 0.5f * m0 : m0 * (float)(q * 2)     * rdiv;
      const float w1 = one_sib ? 0.5f * m1 : m1 * (float)(q * 2 + 1) * rdiv;
      wlds[node][q * 2]     = make_float4(m0, m0, w0, w0);
      wlds[node][q * 2 + 1] = make_float4(m1, m1, w1, w1);
    }

    // ---- phase B: gather, wave w rows [w*8, w*8+8), one node per pass ----
    #pragma unroll
    for (int p = 0; p < 8; ++p){
      const int row = (w << 3) + p;
      const int gn = n0 + row;
      const int4* chp4 = (const int4*)(children + (rowbase + gn) * NC);
      const int4 v0 = chp4[0], v1 = chp4[1], v2 = chp4[2], v3 = chp4[3];

      // issue all 17 coalesced loads (16-deep MLP, 2 lines per instruction)
      const unsigned sv = GLD(gn);
      const unsigned c0  = GLD(v0.x), c1  = GLD(v0.y), c2  = GLD(v0.z), c3  = GLD(v0.w);
      const unsigned c4  = GLD(v1.x), c5  = GLD(v1.y), c6  = GLD(v1.z), c7  = GLD(v1.w);
      const unsigned c8  = GLD(v2.x), c9  = GLD(v2.y), c10 = GLD(v2.z), c11 = GLD(v2.w);
      const unsigned c12 = GLD(v3.x), c13 = GLD(v3.y), c14 = GLD(v3.z), c15 = GLD(v3.w);
      __builtin_amdgcn_sched_barrier(0);

      f32x2 sA = (f32x2){0.f,0.f}, rA = (f32x2){0.f,0.f};
      PRCW(0,  c0)  PRCW(1,  c1)  PRCW(2,  c2)  PRCW(3,  c3)
      PRCW(4,  c4)  PRCW(5,  c5)  PRCW(6,  c6)  PRCW(7,  c7)
      PRCW(8,  c8)  PRCW(9,  c9)  PRCW(10, c10) PRCW(11, c11)
      PRCW(12, c12) PRCW(13, c13) PRCW(14, c14) PRCW(15, c15)
      const f32x2 lA = sA - rA;

      // write wf row: self dword + packed R + packed L (swizzle uniform per wave)
      const unsigned uR = (unsigned)f2bf(rA[0]) | ((unsigned)f2bf(rA[1]) << 16);
      const unsigned uL = (unsigned)f2bf(lA[0]) | ((unsigned)f2bf(lA[1]) << 16);
      const int sw = (row & 7) << 4;
      unsigned char* rp = wf_raw + row * 768;
      *(unsigned*)(rp + (((lane << 2)      ) ^ sw)) = sv;
      *(unsigned*)(rp + ((256 + (lane << 2)) ^ sw)) = uR;
      *(unsigned*)(rp + ((512 + (lane << 2)) ^ sw)) = uL;
    }
  } else {
    // f32 fallback: R10 gather (8 thr/node, 16 dims)
    const int nloc = t >> 3;
    const int q = t & 7;
    const int d0 = q * 16;
    const int gn = n0 + nloc;
    const int4* chp4 = (const int4*)(children + (rowbase + gn) * NC);
    int ns = 0;
    #pragma unroll
    for (int c4 = 0; c4 < 4; ++c4){
      int4 v = chp4[c4];
      ns += (v.x > 0) + (v.y > 0) + (v.z > 0) + (v.w > 0);
    }
    const float rdiv = 1.0f / (float)(((ns - 1) > 1) ? (ns - 1) : 1);
    const bool one_sib = (ns == 1);
    const float* sp = nodeEmb + (rowbase + gn) * ND + d0;
    float sv[16];
    #pragma unroll
    for (int j = 0; j < 4; ++j){
      float4 s = *(const float4*)(sp + j * 4);
      sv[j*4+0]=s.x; sv[j*4+1]=s.y; sv[j*4+2]=s.z; sv[j*4+3]=s.w;
    }
    st8(wf_raw, 768, nloc, 2 * d0, sv);
    st8(wf_raw, 768, nloc, 2 * (d0 + 8), sv + 8);
    float aR[16], aL[16];
    #pragma unroll
    for (int i = 0; i < 16; ++i){ aR[i] = 0.0f; aL[i] = 0.0f; }
    #pragma unroll
    for (int c4 = 0; c4 < 4; ++c4){
      int4 v = chp4[c4];
      int cidx[4] = {v.x, v.y, v.z, v.w};
      #pragma unroll
      for (int jj = 0; jj < 4; ++jj){
        const int c = c4 * 4 + jj;
        const int idx = cidx[jj];
        const float mk  = (idx > 0) ? 1.0f : 0.0f;
        const float wrc = one_sib ? (0.5f * mk) : (mk * (float)c * rdiv);
        const float wlc = (1.0f - wrc) * mk;
        const float* cp = nodeEmb + (rowbase + idx) * ND + d0;
        #pragma unroll
        for (int j = 0; j < 4; ++j){
          float4 u = *(const float4*)(cp + j * 4);
          aR[j*4+0] += wrc * u.x; aL[j*4+0] += wlc * u.x;
          aR[j*4+1] += wrc * u.y; aL[j*4+1] += wlc * u.y;
          aR[j*4+2] += wrc * u.z; aL[j*4+2] += wlc * u.z;
          aR[j*4+3] += wrc * u.w; aL[j*4+3] += wlc * u.w;
        }
      }
    }
    st8(wf_raw, 768, nloc, 2 * (ND + d0),         aR);
    st8(wf_raw, 768, nloc, 2 * (ND + d0 + 8),     aR + 8);
    st8(wf_raw, 768, nloc, 2 * (2 * ND + d0),     aL);
    st8(wf_raw, 768, nloc, 2 * (2 * ND + d0 + 8), aL + 8);
  }
  __syncthreads();

  // ---- MFMA: 32 rows x 32 cols per wave, K=384; B frags streamed (L2-hot) ----
  {
    f32x4 acc[2][2];
    #pragma unroll
    for (int rf = 0; rf < 2; ++rf){
      acc[rf][0] = (f32x4){0.f, 0.f, 0.f, 0.f};
      acc[rf][1] = (f32x4){0.f, 0.f, 0.f, 0.f};
    }
    #pragma unroll 4
    for (int ks = 0; ks < 12; ++ks){
      bf16x8 B0 = __builtin_bit_cast(bf16x8, w1frag[((w * 2 + 0) * 12 + ks) * 64 + lane]);
      bf16x8 B1 = __builtin_bit_cast(bf16x8, w1frag[((w * 2 + 1) * 12 + ks) * 64 + lane]);
      const int koff = ks * 64 + ((lane >> 4) << 4);
      #pragma unroll
      for (int rf = 0; rf < 2; ++rf){
        const int row = rf * 16 + (lane & 15);
        bf16x8 a = __builtin_bit_cast(bf16x8, ldq(wf_raw, 768, row, koff));
        acc[rf][0] = __builtin_amdgcn_mfma_f32_16x16x32_bf16(a, B0, acc[rf][0], 0, 0, 0);
        acc[rf][1] = __builtin_amdgcn_mfma_f32_16x16x32_bf16(a, B1, acc[rf][1], 0, 0, 0);
      }
    }

    float m0 = -3.0e38f, m1 = -3.0e38f;
    #pragma unroll
    for (int rf = 0; rf < 2; ++rf)
      #pragma unroll
      for (int i = 0; i < 4; ++i){
        m0 = fmaxf(m0, acc[rf][0][i]);
        m1 = fmaxf(m1, acc[rf][1][i]);
      }
    m0 = fmaxf(m0, __shfl_xor(m0, 16, 64));
    m0 = fmaxf(m0, __shfl_xor(m0, 32, 64));
    m1 = fmaxf(m1, __shfl_xor(m1, 16, 64));
    m1 = fmaxf(m1, __shfl_xor(m1, 32, 64));
    if (lane < 16){
      atomicMax(pooled + b * NH + w * 32 + lane,      enc_f32(m0));
      atomicMax(pooled + b * NH + w * 32 + 16 + lane, enc_f32(m1));
    }
  }
}

// ---- final: h=tanh(pooled+b1) -> MFMA h@W2 -> tanh -> cosine(v1,v2) ----
__global__ __launch_bounds__(256) void tbcnn_final(
    const unsigned* __restrict__ pooled, const float* __restrict__ b1,
    const uint4* __restrict__ w2frag, const float* __restrict__ b2,
    float* __restrict__ out)
{
  __shared__ __align__(16) unsigned char hls[NB * 256];   // 32 x 128 bf16, swizzled
  __shared__ float os[NB * NH];
  const int t = threadIdx.x;
  const int lane = t & 63;
  const int w = t >> 6;

  {
    const int row = t >> 3;          // batch
    const int q = t & 7;
    const int d0 = q * 16;
    const unsigned* pp = pooled + row * NH + d0;
    const float* bp = b1 + d0;
    float hv[16];
    #pragma unroll
    for (int j = 0; j < 16; ++j) hv[j] = tanhf(dec_f32(pp[j]) + bp[j]);
    st8(hls, 256, row, 2 * d0, hv);
    st8(hls, 256, row, 2 * (d0 + 8), hv + 8);
  }
  __syncthreads();
  {
    f32x4 acc[2][2];
    #pragma unroll
    for (int rf = 0; rf < 2; ++rf){
      acc[rf][0] = (f32x4){0.f,0.f,0.f,0.f};
      acc[rf][1] = (f32x4){0.f,0.f,0.f,0.f};
    }
    #pragma unroll
    for (int ks = 0; ks < 4; ++ks){
      bf16x8 B0 = __builtin_bit_cast(bf16x8, w2frag[((w * 2 + 0) * 4 + ks) * 64 + lane]);
      bf16x8 B1 = __builtin_bit_cast(bf16x8, w2frag[((w * 2 + 1) * 4 + ks) * 64 + lane]);
      const int koff = ks * 64 + ((lane >> 4) << 4);
      #pragma unroll
      for (int rf = 0; rf < 2; ++rf){
        bf16x8 a = __builtin_bit_cast(bf16x8, ldq(hls, 256, rf * 16 + (lane & 15), koff));
        acc[rf][0] = __builtin_amdgcn_mfma_f32_16x16x32_bf16(a, B0, acc[rf][0], 0, 0, 0);
        acc[rf][1] = __builtin_amdgcn_mfma_f32_16x16x32_bf16(a, B1, acc[rf][1], 0, 0, 0);
      }
    }
    #pragma unroll
    for (int rf = 0; rf < 2; ++rf)
      #pragma unroll
      for (int cf = 0; cf < 2; ++cf){
        const int col = w * 32 + cf * 16 + (lane & 15);
        const float bias = b2[col];
        #pragma unroll
        for (int i = 0; i < 4; ++i){
          const int r = rf * 16 + (lane >> 4) * 4 + i;
          os[r * NH + col] = tanhf(acc[rf][cf][i] + bias);
        }
      }
  }
  __syncthreads();
  if (t < 16){
    float s12 = 0.f, s11 = 0.f, s22 = 0.f;
    #pragma unroll 4
    for (int d = 0; d < NH; ++d){
      float a = os[t * NH + d];
      float c = os[(t + 16) * NH + d];
      s12 += a * c; s11 += a * a; s22 += c * c;
    }
    float n1 = fmaxf(sqrtf(s11), 1e-8f);
    float n2 = fmaxf(sqrtf(s22), 1e-8f);
    out[t] = s12 / (n1 * n2);
  }
}

extern "C" void kernel_launch(void* const* d_in, const int* in_sizes, int n_in,
                              void* d_out, int out_size, void* d_ws, size_t ws_size,
                              hipStream_t stream)
{
  const int*   children = (const int*)d_in[0];
  const float* nodeEmb  = (const float*)d_in[1];
  const float* W1       = (const float*)d_in[2];
  const float* b1       = (const float*)d_in[3];
  const float* W2       = (const float*)d_in[4];
  const float* b2       = (const float*)d_in[5];
  float* out = (float*)d_out;

  unsigned* pooled = (unsigned*)((char*)d_ws + OFF_POOLED);
  uint4* w1frag    = (uint4*)((char*)d_ws + OFF_W1);
  uint4* w2frag    = (uint4*)((char*)d_ws + OFF_W2);
  ushort* embBf    = (ushort*)((char*)d_ws + OFF_EMB);

  const bool bf = (ws_size >= WS_NEED_BF);

  tbcnn_prep<<<2080, 256, 0, stream>>>(nodeEmb, W1, W2, pooled, w1frag, w2frag, embBf, bf ? 1 : 0);
  if (bf)
    tbcnn_main<true><<<NBLK, 256, 0, stream>>>(children, nodeEmb, embBf, w1frag, pooled);
  else
    tbcnn_main<false><<<NBLK, 256, 0, stream>>>(children, nodeEmb, embBf, w1frag, pooled);
  tbcnn_final<<<1, 256, 0, stream>>>(pooled, b1, w2frag, b2, out);
}

// Round 13
// 41.324 us; speedup vs baseline: 1.4604x; 1.2880x over previous
//
#include <hip/hip_runtime.h>

#define NB 32
#define NN 2048
#define NC 16
#define ND 128
#define NH 128
#define TM 32
#define NBLK (NB * (NN / TM))   // 2048 blocks of 256 threads

typedef __bf16 bf16x8 __attribute__((ext_vector_type(8)));
typedef float f32x4 __attribute__((ext_vector_type(4)));
typedef float f32x2 __attribute__((ext_vector_type(2)));

__device__ __forceinline__ unsigned short f2bf(float f){
  unsigned u = __float_as_uint(f);
  u = (u + 0x7fffu + ((u >> 16) & 1u)) >> 16;   // RNE
  return (unsigned short)u;
}
__device__ __forceinline__ unsigned enc_f32(float x){
  unsigned u = __float_as_uint(x);
  return (u & 0x80000000u) ? ~u : (u | 0x80000000u);
}
__device__ __forceinline__ float dec_f32(unsigned u){
  return __uint_as_float((u & 0x80000000u) ? (u & 0x7fffffffu) : ~u);
}
// 4 f32 -> 4 fp8 (HW encode; format matches HW decode on this chip)
__device__ __forceinline__ unsigned pack4f8(float a, float b, float c, float d){
  int r = __builtin_amdgcn_cvt_pk_fp8_f32(a, b, 0, false);
  r = __builtin_amdgcn_cvt_pk_fp8_f32(c, d, r, true);
  return (unsigned)r;
}

// swizzled LDS tile helpers (XOR bank swizzle: byte ^= (row&7)<<4)
__device__ __forceinline__ void stq(unsigned char* base, int stride, int row, int koff, uint4 u){
  *(uint4*)(base + row * stride + (koff ^ ((row & 7) << 4))) = u;
}
__device__ __forceinline__ void st8(unsigned char* base, int stride, int row, int koff, const float* f){
  uint4 u;
  u.x = (unsigned)f2bf(f[0]) | ((unsigned)f2bf(f[1]) << 16);
  u.y = (unsigned)f2bf(f[2]) | ((unsigned)f2bf(f[3]) << 16);
  u.z = (unsigned)f2bf(f[4]) | ((unsigned)f2bf(f[5]) << 16);
  u.w = (unsigned)f2bf(f[6]) | ((unsigned)f2bf(f[7]) << 16);
  stq(base, stride, row, koff, u);
}
// pack 4 f32x2 pairs (8 floats) -> 16B bf16 store
__device__ __forceinline__ void st8p(unsigned char* base, int stride, int row, int koff, const f32x2* p){
  uint4 u;
  u.x = (unsigned)f2bf(p[0][0]) | ((unsigned)f2bf(p[0][1]) << 16);
  u.y = (unsigned)f2bf(p[1][0]) | ((unsigned)f2bf(p[1][1]) << 16);
  u.z = (unsigned)f2bf(p[2][0]) | ((unsigned)f2bf(p[2][1]) << 16);
  u.w = (unsigned)f2bf(p[3][0]) | ((unsigned)f2bf(p[3][1]) << 16);
  stq(base, stride, row, koff, u);
}
__device__ __forceinline__ uint4 ldq(const unsigned char* base, int stride, int row, int koff){
  return *(const uint4*)(base + row * stride + (koff ^ ((row & 7) << 4)));
}

// ws layout
#define OFF_POOLED 0
#define OFF_W1     16384
#define OFF_W2     114688
#define OFF_EMB    147456
#define WS_NEED_F8 (OFF_EMB + (size_t)NB*NN*ND)   // fp8: 1 B/elem

// ---- unified prep ----
// blocks [0,2048): nodeEmb f32 -> fp8 e4m3 (HW cvt), XCD-affine
// blocks [2048,2072): W1 frags [cf][ks][lane]x16B ; pooled init
// blocks [2072,2080): W2 frags [cf][ks][lane]x16B
__global__ __launch_bounds__(256) void tbcnn_prep(
    const float* __restrict__ nodeEmb, const float* __restrict__ W1,
    const float* __restrict__ W2, unsigned* __restrict__ pooled,
    uint4* __restrict__ w1frag, uint4* __restrict__ w2frag,
    unsigned char* __restrict__ embF8, int doEmb)
{
  const int blk = blockIdx.x;
  const int t = threadIdx.x;
  if (blk < 2048){
    if (!doEmb) return;
    // chunk covers 16 floats -> 16B fp8; XCD x owns batches 4x..4x+3 (matches main)
    const int chk = ((blk & 7) << 8) | (blk >> 3);
    const int tid = chk * 256 + t;                // 0..524287
    const float4* src = (const float4*)nodeEmb;
    float4 v0 = src[tid * 4 + 0];
    float4 v1 = src[tid * 4 + 1];
    float4 v2 = src[tid * 4 + 2];
    float4 v3 = src[tid * 4 + 3];
    uint4 o;
    o.x = pack4f8(v0.x, v0.y, v0.z, v0.w);
    o.y = pack4f8(v1.x, v1.y, v1.z, v1.w);
    o.z = pack4f8(v2.x, v2.y, v2.z, v2.w);
    o.w = pack4f8(v3.x, v3.y, v3.z, v3.w);
    ((uint4*)embF8)[tid] = o;
  } else if (blk < 2072){
    const int tt = (blk - 2048) * 256 + t;        // 0..6143
    if (tt < NB * NH) pooled[tt] = 0u;            // enc-min (any real value wins)
    const int lane = tt & 63;
    const int rest = tt >> 6;                     // 0..95
    const int ks = rest % 12;
    const int cf = rest / 12;
    const int col = (cf >> 1) * 32 + (cf & 1) * 16 + (lane & 15);
    const int k0 = ks * 32 + (lane >> 4) * 8;
    unsigned ps[4];
    #pragma unroll
    for (int p = 0; p < 4; ++p){
      unsigned lo = f2bf(W1[(size_t)(k0 + 2*p) * NH + col]);
      unsigned hi = f2bf(W1[(size_t)(k0 + 2*p + 1) * NH + col]);
      ps[p] = lo | (hi << 16);
    }
    w1frag[tt] = make_uint4(ps[0], ps[1], ps[2], ps[3]);
  } else {
    const int tt = (blk - 2072) * 256 + t;        // 0..2047
    const int lane = tt & 63;
    const int rest = tt >> 6;
    const int ks = rest & 3;
    const int cf = rest >> 2;
    const int col = (cf >> 1) * 32 + (cf & 1) * 16 + (lane & 15);
    const int k0 = ks * 32 + (lane >> 4) * 8;
    unsigned ps[4];
    #pragma unroll
    for (int p = 0; p < 4; ++p){
      unsigned lo = f2bf(W2[(size_t)(k0 + 2*p) * NH + col]);
      unsigned hi = f2bf(W2[(size_t)(k0 + 2*p + 1) * NH + col]);
      ps[p] = lo | (hi << 16);
    }
    w2frag[tt] = make_uint4(ps[0], ps[1], ps[2], ps[3]);
  }
}

// decode one dword (4 fp8) and accumulate into pairs p, p+1 with packed FMA
#define PROCF8(u, p) { \
  f32x2 lo_ = __builtin_amdgcn_cvt_pk_f32_fp8((int)(u), false); \
  f32x2 hi_ = __builtin_amdgcn_cvt_pk_f32_fp8((int)(u), true); \
  aR2[(p)]   += w_r * lo_; aL2[(p)]   += w_l * lo_; \
  aR2[(p)+1] += w_r * hi_; aL2[(p)+1] += w_l * hi_; }

// issue 4 children's 16B fp8 loads (1 line per row — the R13 halving)
#define ISSUE4(vv, D) { \
  D[0] = *(const uint4*)(embF8 + (rowbase + (unsigned)(vv).x) * ND + d0); \
  D[1] = *(const uint4*)(embF8 + (rowbase + (unsigned)(vv).y) * ND + d0); \
  D[2] = *(const uint4*)(embF8 + (rowbase + (unsigned)(vv).z) * ND + d0); \
  D[3] = *(const uint4*)(embF8 + (rowbase + (unsigned)(vv).w) * ND + d0); }

#define CW(c, idx) \
  const float mk  = ((idx) > 0) ? 1.0f : 0.0f; \
  const float wrc = one_sib ? (0.5f * mk) : (mk * (float)(c) * rdiv); \
  const float wlc = (1.0f - wrc) * mk; \
  const f32x2 w_r = (f32x2){wrc, wrc}; \
  const f32x2 w_l = (f32x2){wlc, wlc};

// process 4 children of group g from staged buffer U
#define PROC4(g, vv, U) { \
  { CW(4*(g)+0, (vv).x) PROCF8(U[0].x,0) PROCF8(U[0].y,2) PROCF8(U[0].z,4) PROCF8(U[0].w,6) } \
  { CW(4*(g)+1, (vv).y) PROCF8(U[1].x,0) PROCF8(U[1].y,2) PROCF8(U[1].z,4) PROCF8(U[1].w,6) } \
  { CW(4*(g)+2, (vv).z) PROCF8(U[2].x,0) PROCF8(U[2].y,2) PROCF8(U[2].z,4) PROCF8(U[2].w,6) } \
  { CW(4*(g)+3, (vv).w) PROCF8(U[3].x,0) PROCF8(U[3].y,2) PROCF8(U[3].z,4) PROCF8(U[3].w,6) } }

// ---- main: fp8 pipelined gather + wf (LDS) + MFMA + atomicMax ----
// Kept lessons: (256,2) only (R2/R4 spill); no fence/ticket (R5/R9); R10 layout
// (R11/R12 wave-per-node was net worse); sched_barrier staging (R7/R8).
template<bool F8>
__global__ __launch_bounds__(256, 2) void tbcnn_main(
    const int* __restrict__ children, const float* __restrict__ nodeEmb,
    const unsigned char* __restrict__ embF8, const uint4* __restrict__ w1frag,
    unsigned* __restrict__ pooled)
{
  __shared__ __align__(16) unsigned char wf_raw[TM * 768];   // 24 KB
  // XCD-aware swizzle: 2048 blocks = 8 XCDs x 256; each XCD owns 4 batches
  const int j0 = ((blockIdx.x & 7) << 8) | (blockIdx.x >> 3);
  const int b = j0 >> 6;
  const int n0 = (j0 & 63) * TM;
  const int t = threadIdx.x;
  const int lane = t & 63;
  const int w = t >> 6;
  const size_t rowbase = (size_t)b * NN;

  // ---- gather phase: 8 threads per node, 16 dims each ----
  {
    const int nloc = t >> 3;
    const int q = t & 7;
    const int d0 = q * 16;          // dim == byte offset in fp8 row
    const int gn = n0 + nloc;
    const int4* chp4 = (const int4*)(children + (rowbase + gn) * NC);

    const int4 vA = chp4[0], vB = chp4[1], vC = chp4[2], vD = chp4[3];
    int ns = (vA.x > 0) + (vA.y > 0) + (vA.z > 0) + (vA.w > 0)
           + (vB.x > 0) + (vB.y > 0) + (vB.z > 0) + (vB.w > 0)
           + (vC.x > 0) + (vC.y > 0) + (vC.z > 0) + (vC.w > 0)
           + (vD.x > 0) + (vD.y > 0) + (vD.z > 0) + (vD.w > 0);
    const float rdiv = 1.0f / (float)(((ns - 1) > 1) ? (ns - 1) : 1);
    const bool one_sib = (ns == 1);

    if (F8){
      f32x2 aR2[8], aL2[8];
      #pragma unroll
      for (int i = 0; i < 8; ++i){ aR2[i] = (f32x2){0.f,0.f}; aL2[i] = (f32x2){0.f,0.f}; }

      uint4 g0[4], g1[4];
      // issue self + groups A,B (9 loads in flight)
      const uint4 sq = *(const uint4*)(embF8 + (rowbase + gn) * ND + d0);
      ISSUE4(vA, g0)
      ISSUE4(vB, g1)
      __builtin_amdgcn_sched_barrier(0);
      // convert+store self (hides A/B latency), then process A, refill with C
      {
        f32x2 sv[8];
        sv[0] = __builtin_amdgcn_cvt_pk_f32_fp8((int)sq.x, false);
        sv[1] = __builtin_amdgcn_cvt_pk_f32_fp8((int)sq.x, true);
        sv[2] = __builtin_amdgcn_cvt_pk_f32_fp8((int)sq.y, false);
        sv[3] = __builtin_amdgcn_cvt_pk_f32_fp8((int)sq.y, true);
        sv[4] = __builtin_amdgcn_cvt_pk_f32_fp8((int)sq.z, false);
        sv[5] = __builtin_amdgcn_cvt_pk_f32_fp8((int)sq.z, true);
        sv[6] = __builtin_amdgcn_cvt_pk_f32_fp8((int)sq.w, false);
        sv[7] = __builtin_amdgcn_cvt_pk_f32_fp8((int)sq.w, true);
        st8p(wf_raw, 768, nloc, 2 * d0,       sv);
        st8p(wf_raw, 768, nloc, 2 * (d0 + 8), sv + 4);
      }
      PROC4(0, vA, g0)
      ISSUE4(vC, g0)
      __builtin_amdgcn_sched_barrier(0);
      PROC4(1, vB, g1)
      ISSUE4(vD, g1)
      __builtin_amdgcn_sched_barrier(0);
      PROC4(2, vC, g0)
      __builtin_amdgcn_sched_barrier(0);
      PROC4(3, vD, g1)

      st8p(wf_raw, 768, nloc, 2 * (ND + d0),         aR2);
      st8p(wf_raw, 768, nloc, 2 * (ND + d0 + 8),     aR2 + 4);
      st8p(wf_raw, 768, nloc, 2 * (2 * ND + d0),     aL2);
      st8p(wf_raw, 768, nloc, 2 * (2 * ND + d0 + 8), aL2 + 4);
    } else {
      // f32 fallback (ws too small): R10 structure
      const float* sp = nodeEmb + (rowbase + gn) * ND + d0;
      float sv[16];
      #pragma unroll
      for (int j = 0; j < 4; ++j){
        float4 s = *(const float4*)(sp + j * 4);
        sv[j*4+0]=s.x; sv[j*4+1]=s.y; sv[j*4+2]=s.z; sv[j*4+3]=s.w;
      }
      st8(wf_raw, 768, nloc, 2 * d0, sv);
      st8(wf_raw, 768, nloc, 2 * (d0 + 8), sv + 8);
      float aR[16], aL[16];
      #pragma unroll
      for (int i = 0; i < 16; ++i){ aR[i] = 0.0f; aL[i] = 0.0f; }
      const int4 vs[4] = {vA, vB, vC, vD};
      #pragma unroll
      for (int c4 = 0; c4 < 4; ++c4){
        int cidx[4] = {vs[c4].x, vs[c4].y, vs[c4].z, vs[c4].w};
        #pragma unroll
        for (int jj = 0; jj < 4; ++jj){
          const int c = c4 * 4 + jj;
          const int idx = cidx[jj];
          const float mk  = (idx > 0) ? 1.0f : 0.0f;
          const float wrc = one_sib ? (0.5f * mk) : (mk * (float)c * rdiv);
          const float wlc = (1.0f - wrc) * mk;
          const float* cp = nodeEmb + (rowbase + idx) * ND + d0;
          #pragma unroll
          for (int j = 0; j < 4; ++j){
            float4 u = *(const float4*)(cp + j * 4);
            aR[j*4+0] += wrc * u.x; aL[j*4+0] += wlc * u.x;
            aR[j*4+1] += wrc * u.y; aL[j*4+1] += wlc * u.y;
            aR[j*4+2] += wrc * u.z; aL[j*4+2] += wlc * u.z;
            aR[j*4+3] += wrc * u.w; aL[j*4+3] += wlc * u.w;
          }
        }
      }
      st8(wf_raw, 768, nloc, 2 * (ND + d0),         aR);
      st8(wf_raw, 768, nloc, 2 * (ND + d0 + 8),     aR + 8);
      st8(wf_raw, 768, nloc, 2 * (2 * ND + d0),     aL);
      st8(wf_raw, 768, nloc, 2 * (2 * ND + d0 + 8), aL + 8);
    }
  }
  __syncthreads();

  // ---- MFMA: 32 rows x 32 cols per wave, K=384; B frags streamed (L2-hot) ----
  {
    f32x4 acc[2][2];
    #pragma unroll
    for (int rf = 0; rf < 2; ++rf){
      acc[rf][0] = (f32x4){0.f, 0.f, 0.f, 0.f};
      acc[rf][1] = (f32x4){0.f, 0.f, 0.f, 0.f};
    }
    #pragma unroll 4
    for (int ks = 0; ks < 12; ++ks){
      bf16x8 B0 = __builtin_bit_cast(bf16x8, w1frag[((w * 2 + 0) * 12 + ks) * 64 + lane]);
      bf16x8 B1 = __builtin_bit_cast(bf16x8, w1frag[((w * 2 + 1) * 12 + ks) * 64 + lane]);
      const int koff = ks * 64 + ((lane >> 4) << 4);
      #pragma unroll
      for (int rf = 0; rf < 2; ++rf){
        const int row = rf * 16 + (lane & 15);
        bf16x8 a = __builtin_bit_cast(bf16x8, ldq(wf_raw, 768, row, koff));
        acc[rf][0] = __builtin_amdgcn_mfma_f32_16x16x32_bf16(a, B0, acc[rf][0], 0, 0, 0);
        acc[rf][1] = __builtin_amdgcn_mfma_f32_16x16x32_bf16(a, B1, acc[rf][1], 0, 0, 0);
      }
    }

    float m0 = -3.0e38f, m1 = -3.0e38f;
    #pragma unroll
    for (int rf = 0; rf < 2; ++rf)
      #pragma unroll
      for (int i = 0; i < 4; ++i){
        m0 = fmaxf(m0, acc[rf][0][i]);
        m1 = fmaxf(m1, acc[rf][1][i]);
      }
    m0 = fmaxf(m0, __shfl_xor(m0, 16, 64));
    m0 = fmaxf(m0, __shfl_xor(m0, 32, 64));
    m1 = fmaxf(m1, __shfl_xor(m1, 16, 64));
    m1 = fmaxf(m1, __shfl_xor(m1, 32, 64));
    if (lane < 16){
      atomicMax(pooled + b * NH + w * 32 + lane,      enc_f32(m0));
      atomicMax(pooled + b * NH + w * 32 + 16 + lane, enc_f32(m1));
    }
  }
}

// ---- final: h=tanh(pooled+b1) -> MFMA h@W2 -> tanh -> cosine(v1,v2) ----
__global__ __launch_bounds__(256) void tbcnn_final(
    const unsigned* __restrict__ pooled, const float* __restrict__ b1,
    const uint4* __restrict__ w2frag, const float* __restrict__ b2,
    float* __restrict__ out)
{
  __shared__ __align__(16) unsigned char hls[NB * 256];   // 32 x 128 bf16, swizzled
  __shared__ float os[NB * NH];
  const int t = threadIdx.x;
  const int lane = t & 63;
  const int w = t >> 6;

  {
    const int row = t >> 3;          // batch
    const int q = t & 7;
    const int d0 = q * 16;
    const unsigned* pp = pooled + row * NH + d0;
    const float* bp = b1 + d0;
    float hv[16];
    #pragma unroll
    for (int j = 0; j < 16; ++j) hv[j] = tanhf(dec_f32(pp[j]) + bp[j]);
    st8(hls, 256, row, 2 * d0, hv);
    st8(hls, 256, row, 2 * (d0 + 8), hv + 8);
  }
  __syncthreads();
  {
    f32x4 acc[2][2];
    #pragma unroll
    for (int rf = 0; rf < 2; ++rf){
      acc[rf][0] = (f32x4){0.f,0.f,0.f,0.f};
      acc[rf][1] = (f32x4){0.f,0.f,0.f,0.f};
    }
    #pragma unroll
    for (int ks = 0; ks < 4; ++ks){
      bf16x8 B0 = __builtin_bit_cast(bf16x8, w2frag[((w * 2 + 0) * 4 + ks) * 64 + lane]);
      bf16x8 B1 = __builtin_bit_cast(bf16x8, w2frag[((w * 2 + 1) * 4 + ks) * 64 + lane]);
      const int koff = ks * 64 + ((lane >> 4) << 4);
      #pragma unroll
      for (int rf = 0; rf < 2; ++rf){
        bf16x8 a = __builtin_bit_cast(bf16x8, ldq(hls, 256, rf * 16 + (lane & 15), koff));
        acc[rf][0] = __builtin_amdgcn_mfma_f32_16x16x32_bf16(a, B0, acc[rf][0], 0, 0, 0);
        acc[rf][1] = __builtin_amdgcn_mfma_f32_16x16x32_bf16(a, B1, acc[rf][1], 0, 0, 0);
      }
    }
    #pragma unroll
    for (int rf = 0; rf < 2; ++rf)
      #pragma unroll
      for (int cf = 0; cf < 2; ++cf){
        const int col = w * 32 + cf * 16 + (lane & 15);
        const float bias = b2[col];
        #pragma unroll
        for (int i = 0; i < 4; ++i){
          const int r = rf * 16 + (lane >> 4) * 4 + i;
          os[r * NH + col] = tanhf(acc[rf][cf][i] + bias);
        }
      }
  }
  __syncthreads();
  if (t < 16){
    float s12 = 0.f, s11 = 0.f, s22 = 0.f;
    #pragma unroll 4
    for (int d = 0; d < NH; ++d){
      float a = os[t * NH + d];
      float c = os[(t + 16) * NH + d];
      s12 += a * c; s11 += a * a; s22 += c * c;
    }
    float n1 = fmaxf(sqrtf(s11), 1e-8f);
    float n2 = fmaxf(sqrtf(s22), 1e-8f);
    out[t] = s12 / (n1 * n2);
  }
}

extern "C" void kernel_launch(void* const* d_in, const int* in_sizes, int n_in,
                              void* d_out, int out_size, void* d_ws, size_t ws_size,
                              hipStream_t stream)
{
  const int*   children = (const int*)d_in[0];
  const float* nodeEmb  = (const float*)d_in[1];
  const float* W1       = (const float*)d_in[2];
  const float* b1       = (const float*)d_in[3];
  const float* W2       = (const float*)d_in[4];
  const float* b2       = (const float*)d_in[5];
  float* out = (float*)d_out;

  unsigned* pooled      = (unsigned*)((char*)d_ws + OFF_POOLED);
  uint4* w1frag         = (uint4*)((char*)d_ws + OFF_W1);
  uint4* w2frag         = (uint4*)((char*)d_ws + OFF_W2);
  unsigned char* embF8  = (unsigned char*)((char*)d_ws + OFF_EMB);

  const bool f8 = (ws_size >= WS_NEED_F8);

  tbcnn_prep<<<2080, 256, 0, stream>>>(nodeEmb, W1, W2, pooled, w1frag, w2frag, embF8, f8 ? 1 : 0);
  if (f8)
    tbcnn_main<true><<<NBLK, 256, 0, stream>>>(children, nodeEmb, embF8, w1frag, pooled);
  else
    tbcnn_main<false><<<NBLK, 256, 0, stream>>>(children, nodeEmb, embF8, w1frag, pooled);
  tbcnn_final<<<1, 256, 0, stream>>>(pooled, b1, w2frag, b2, out);
}

// Round 14
// 40.909 us; speedup vs baseline: 1.4752x; 1.0101x over previous
//
#include <hip/hip_runtime.h>

#define NB 32
#define NN 2048
#define NC 16
#define ND 128
#define NH 128
#define TM 64
#define NBLK (NB * (NN / TM))   // 1024 blocks of 256 threads

typedef __bf16 bf16x8 __attribute__((ext_vector_type(8)));
typedef float f32x4 __attribute__((ext_vector_type(4)));
typedef float f32x2 __attribute__((ext_vector_type(2)));

__device__ __forceinline__ unsigned short f2bf(float f){
  unsigned u = __float_as_uint(f);
  u = (u + 0x7fffu + ((u >> 16) & 1u)) >> 16;   // RNE
  return (unsigned short)u;
}
__device__ __forceinline__ unsigned enc_f32(float x){
  unsigned u = __float_as_uint(x);
  return (u & 0x80000000u) ? ~u : (u | 0x80000000u);
}
__device__ __forceinline__ float dec_f32(unsigned u){
  return __uint_as_float((u & 0x80000000u) ? (u & 0x7fffffffu) : ~u);
}
// 4 f32 -> 4 fp8 (HW encode; matches HW decode)
__device__ __forceinline__ unsigned pack4f8(float a, float b, float c, float d){
  int r = __builtin_amdgcn_cvt_pk_fp8_f32(a, b, 0, false);
  r = __builtin_amdgcn_cvt_pk_fp8_f32(c, d, r, true);
  return (unsigned)r;
}

// swizzled LDS tile helpers (XOR bank swizzle: byte ^= (row&7)<<4)
__device__ __forceinline__ void stq(unsigned char* base, int stride, int row, int koff, uint4 u){
  *(uint4*)(base + row * stride + (koff ^ ((row & 7) << 4))) = u;
}
__device__ __forceinline__ void st8(unsigned char* base, int stride, int row, int koff, const float* f){
  uint4 u;
  u.x = (unsigned)f2bf(f[0]) | ((unsigned)f2bf(f[1]) << 16);
  u.y = (unsigned)f2bf(f[2]) | ((unsigned)f2bf(f[3]) << 16);
  u.z = (unsigned)f2bf(f[4]) | ((unsigned)f2bf(f[5]) << 16);
  u.w = (unsigned)f2bf(f[6]) | ((unsigned)f2bf(f[7]) << 16);
  stq(base, stride, row, koff, u);
}
// pack 4 f32x2 pairs (8 floats) -> 16B bf16 store
__device__ __forceinline__ void st8p(unsigned char* base, int stride, int row, int koff, const f32x2* p){
  uint4 u;
  u.x = (unsigned)f2bf(p[0][0]) | ((unsigned)f2bf(p[0][1]) << 16);
  u.y = (unsigned)f2bf(p[1][0]) | ((unsigned)f2bf(p[1][1]) << 16);
  u.z = (unsigned)f2bf(p[2][0]) | ((unsigned)f2bf(p[2][1]) << 16);
  u.w = (unsigned)f2bf(p[3][0]) | ((unsigned)f2bf(p[3][1]) << 16);
  stq(base, stride, row, koff, u);
}
__device__ __forceinline__ uint4 ldq(const unsigned char* base, int stride, int row, int koff){
  return *(const uint4*)(base + row * stride + (koff ^ ((row & 7) << 4)));
}

// ws layout
#define OFF_POOLED 0
#define OFF_W1     16384
#define OFF_W2     114688
#define OFF_EMB    147456
#define WS_NEED_F8 (OFF_EMB + (size_t)NB*NN*ND)   // fp8: 1 B/elem

// ---- unified prep ----
// blocks [0,2048): nodeEmb f32 -> fp8 e4m3 (HW cvt), XCD-affine
// blocks [2048,2072): W1 frags [cf][ks][lane]x16B ; pooled init
// blocks [2072,2080): W2 frags [cf][ks][lane]x16B
__global__ __launch_bounds__(256) void tbcnn_prep(
    const float* __restrict__ nodeEmb, const float* __restrict__ W1,
    const float* __restrict__ W2, unsigned* __restrict__ pooled,
    uint4* __restrict__ w1frag, uint4* __restrict__ w2frag,
    unsigned char* __restrict__ embF8, int doEmb)
{
  const int blk = blockIdx.x;
  const int t = threadIdx.x;
  if (blk < 2048){
    if (!doEmb) return;
    const int chk = ((blk & 7) << 8) | (blk >> 3);
    const int tid = chk * 256 + t;                // 0..524287
    const float4* src = (const float4*)nodeEmb;
    float4 v0 = src[tid * 4 + 0];
    float4 v1 = src[tid * 4 + 1];
    float4 v2 = src[tid * 4 + 2];
    float4 v3 = src[tid * 4 + 3];
    uint4 o;
    o.x = pack4f8(v0.x, v0.y, v0.z, v0.w);
    o.y = pack4f8(v1.x, v1.y, v1.z, v1.w);
    o.z = pack4f8(v2.x, v2.y, v2.z, v2.w);
    o.w = pack4f8(v3.x, v3.y, v3.z, v3.w);
    ((uint4*)embF8)[tid] = o;
  } else if (blk < 2072){
    const int tt = (blk - 2048) * 256 + t;        // 0..6143
    if (tt < NB * NH) pooled[tt] = 0u;            // enc-min (any real value wins)
    const int lane = tt & 63;
    const int rest = tt >> 6;                     // 0..95
    const int ks = rest % 12;
    const int cf = rest / 12;
    const int col = (cf >> 1) * 32 + (cf & 1) * 16 + (lane & 15);
    const int k0 = ks * 32 + (lane >> 4) * 8;
    unsigned ps[4];
    #pragma unroll
    for (int p = 0; p < 4; ++p){
      unsigned lo = f2bf(W1[(size_t)(k0 + 2*p) * NH + col]);
      unsigned hi = f2bf(W1[(size_t)(k0 + 2*p + 1) * NH + col]);
      ps[p] = lo | (hi << 16);
    }
    w1frag[tt] = make_uint4(ps[0], ps[1], ps[2], ps[3]);
  } else {
    const int tt = (blk - 2072) * 256 + t;        // 0..2047
    const int lane = tt & 63;
    const int rest = tt >> 6;
    const int ks = rest & 3;
    const int cf = rest >> 2;
    const int col = (cf >> 1) * 32 + (cf & 1) * 16 + (lane & 15);
    const int k0 = ks * 32 + (lane >> 4) * 8;
    unsigned ps[4];
    #pragma unroll
    for (int p = 0; p < 4; ++p){
      unsigned lo = f2bf(W2[(size_t)(k0 + 2*p) * NH + col]);
      unsigned hi = f2bf(W2[(size_t)(k0 + 2*p + 1) * NH + col]);
      ps[p] = lo | (hi << 16);
    }
    w2frag[tt] = make_uint4(ps[0], ps[1], ps[2], ps[3]);
  }
}

// decode one dword (4 fp8) and accumulate into pairs p, p+1 with packed FMA
#define PROCF8(u, p) { \
  f32x2 lo_ = __builtin_amdgcn_cvt_pk_f32_fp8((int)(u), false); \
  f32x2 hi_ = __builtin_amdgcn_cvt_pk_f32_fp8((int)(u), true); \
  aR2[(p)]   += w_r * lo_; aL2[(p)]   += w_l * lo_; \
  aR2[(p)+1] += w_r * hi_; aL2[(p)+1] += w_l * hi_; }

// issue 4 children's 16B fp8 loads (1 line per row)
#define ISSUE4(vv, D) { \
  D[0] = *(const uint4*)(embF8 + (rowbase + (unsigned)(vv).x) * ND + d0); \
  D[1] = *(const uint4*)(embF8 + (rowbase + (unsigned)(vv).y) * ND + d0); \
  D[2] = *(const uint4*)(embF8 + (rowbase + (unsigned)(vv).z) * ND + d0); \
  D[3] = *(const uint4*)(embF8 + (rowbase + (unsigned)(vv).w) * ND + d0); }

#define CW(c, idx) \
  const float mk  = ((idx) > 0) ? 1.0f : 0.0f; \
  const float wrc = one_sib ? (0.5f * mk) : (mk * (float)(c) * rdiv); \
  const float wlc = (1.0f - wrc) * mk; \
  const f32x2 w_r = (f32x2){wrc, wrc}; \
  const f32x2 w_l = (f32x2){wlc, wlc};

// process 4 children of group g from staged buffer U
#define PROC4(g, vv, U) { \
  { CW(4*(g)+0, (vv).x) PROCF8(U[0].x,0) PROCF8(U[0].y,2) PROCF8(U[0].z,4) PROCF8(U[0].w,6) } \
  { CW(4*(g)+1, (vv).y) PROCF8(U[1].x,0) PROCF8(U[1].y,2) PROCF8(U[1].z,4) PROCF8(U[1].w,6) } \
  { CW(4*(g)+2, (vv).z) PROCF8(U[2].x,0) PROCF8(U[2].y,2) PROCF8(U[2].z,4) PROCF8(U[2].w,6) } \
  { CW(4*(g)+3, (vv).w) PROCF8(U[3].x,0) PROCF8(U[3].y,2) PROCF8(U[3].z,4) PROCF8(U[3].w,6) } }

// ---- main: TM=64 (2 gather passes) fp8 gather + wf (LDS) + MFMA + atomicMax ----
// R14: TM 32->64 halves W1 L2 re-reads (196->98MB) and per-CU block count.
// Kept lessons: (256,2) only (R2/R4 spill); no fence/ticket (R5/R9); R10/R13
// 8-thr-per-node layout (R11/R12 wave-per-node was net worse); sched_barrier
// staging (R7/R8); fp8 rows = 1 line (R13).
template<bool F8>
__global__ __launch_bounds__(256, 2) void tbcnn_main(
    const int* __restrict__ children, const float* __restrict__ nodeEmb,
    const unsigned char* __restrict__ embF8, const uint4* __restrict__ w1frag,
    unsigned* __restrict__ pooled)
{
  __shared__ __align__(16) unsigned char wf_raw[TM * 768];   // 48 KB
  // XCD-aware swizzle: 1024 blocks = 8 XCDs x 128; each XCD owns 4 batches
  const int j0 = ((blockIdx.x & 7) << 7) | (blockIdx.x >> 3);
  const int b = j0 >> 5;
  const int n0 = (j0 & 31) * TM;
  const int t = threadIdx.x;
  const int lane = t & 63;
  const int w = t >> 6;
  const size_t rowbase = (size_t)b * NN;

  // ---- gather: two passes of 32 nodes; 8 threads per node, 16 dims each ----
  #pragma unroll
  for (int pass = 0; pass < 2; ++pass){
    const int nloc = pass * 32 + (t >> 3);
    const int q = t & 7;
    const int d0 = q * 16;          // dim == byte offset in fp8 row
    const int gn = n0 + nloc;
    const int4* chp4 = (const int4*)(children + (rowbase + gn) * NC);

    const int4 vA = chp4[0], vB = chp4[1], vC = chp4[2], vD = chp4[3];
    int ns = (vA.x > 0) + (vA.y > 0) + (vA.z > 0) + (vA.w > 0)
           + (vB.x > 0) + (vB.y > 0) + (vB.z > 0) + (vB.w > 0)
           + (vC.x > 0) + (vC.y > 0) + (vC.z > 0) + (vC.w > 0)
           + (vD.x > 0) + (vD.y > 0) + (vD.z > 0) + (vD.w > 0);
    const float rdiv = 1.0f / (float)(((ns - 1) > 1) ? (ns - 1) : 1);
    const bool one_sib = (ns == 1);

    if (F8){
      f32x2 aR2[8], aL2[8];
      #pragma unroll
      for (int i = 0; i < 8; ++i){ aR2[i] = (f32x2){0.f,0.f}; aL2[i] = (f32x2){0.f,0.f}; }

      uint4 g0[4], g1[4];
      const uint4 sq = *(const uint4*)(embF8 + (rowbase + gn) * ND + d0);
      ISSUE4(vA, g0)
      ISSUE4(vB, g1)
      __builtin_amdgcn_sched_barrier(0);
      {
        f32x2 sv[8];
        sv[0] = __builtin_amdgcn_cvt_pk_f32_fp8((int)sq.x, false);
        sv[1] = __builtin_amdgcn_cvt_pk_f32_fp8((int)sq.x, true);
        sv[2] = __builtin_amdgcn_cvt_pk_f32_fp8((int)sq.y, false);
        sv[3] = __builtin_amdgcn_cvt_pk_f32_fp8((int)sq.y, true);
        sv[4] = __builtin_amdgcn_cvt_pk_f32_fp8((int)sq.z, false);
        sv[5] = __builtin_amdgcn_cvt_pk_f32_fp8((int)sq.z, true);
        sv[6] = __builtin_amdgcn_cvt_pk_f32_fp8((int)sq.w, false);
        sv[7] = __builtin_amdgcn_cvt_pk_f32_fp8((int)sq.w, true);
        st8p(wf_raw, 768, nloc, 2 * d0,       sv);
        st8p(wf_raw, 768, nloc, 2 * (d0 + 8), sv + 4);
      }
      PROC4(0, vA, g0)
      ISSUE4(vC, g0)
      __builtin_amdgcn_sched_barrier(0);
      PROC4(1, vB, g1)
      ISSUE4(vD, g1)
      __builtin_amdgcn_sched_barrier(0);
      PROC4(2, vC, g0)
      __builtin_amdgcn_sched_barrier(0);
      PROC4(3, vD, g1)

      st8p(wf_raw, 768, nloc, 2 * (ND + d0),         aR2);
      st8p(wf_raw, 768, nloc, 2 * (ND + d0 + 8),     aR2 + 4);
      st8p(wf_raw, 768, nloc, 2 * (2 * ND + d0),     aL2);
      st8p(wf_raw, 768, nloc, 2 * (2 * ND + d0 + 8), aL2 + 4);
    } else {
      // f32 fallback (ws too small): R10 structure
      const float* sp = nodeEmb + (rowbase + gn) * ND + d0;
      float sv[16];
      #pragma unroll
      for (int j = 0; j < 4; ++j){
        float4 s = *(const float4*)(sp + j * 4);
        sv[j*4+0]=s.x; sv[j*4+1]=s.y; sv[j*4+2]=s.z; sv[j*4+3]=s.w;
      }
      st8(wf_raw, 768, nloc, 2 * d0, sv);
      st8(wf_raw, 768, nloc, 2 * (d0 + 8), sv + 8);
      float aR[16], aL[16];
      #pragma unroll
      for (int i = 0; i < 16; ++i){ aR[i] = 0.0f; aL[i] = 0.0f; }
      const int4 vs[4] = {vA, vB, vC, vD};
      #pragma unroll
      for (int c4 = 0; c4 < 4; ++c4){
        int cidx[4] = {vs[c4].x, vs[c4].y, vs[c4].z, vs[c4].w};
        #pragma unroll
        for (int jj = 0; jj < 4; ++jj){
          const int c = c4 * 4 + jj;
          const int idx = cidx[jj];
          const float mk  = (idx > 0) ? 1.0f : 0.0f;
          const float wrc = one_sib ? (0.5f * mk) : (mk * (float)c * rdiv);
          const float wlc = (1.0f - wrc) * mk;
          const float* cp = nodeEmb + (rowbase + idx) * ND + d0;
          #pragma unroll
          for (int j = 0; j < 4; ++j){
            float4 u = *(const float4*)(cp + j * 4);
            aR[j*4+0] += wrc * u.x; aL[j*4+0] += wlc * u.x;
            aR[j*4+1] += wrc * u.y; aL[j*4+1] += wlc * u.y;
            aR[j*4+2] += wrc * u.z; aL[j*4+2] += wlc * u.z;
            aR[j*4+3] += wrc * u.w; aL[j*4+3] += wlc * u.w;
          }
        }
      }
      st8(wf_raw, 768, nloc, 2 * (ND + d0),         aR);
      st8(wf_raw, 768, nloc, 2 * (ND + d0 + 8),     aR + 8);
      st8(wf_raw, 768, nloc, 2 * (2 * ND + d0),     aL);
      st8(wf_raw, 768, nloc, 2 * (2 * ND + d0 + 8), aL + 8);
    }
  }
  __syncthreads();

  // ---- MFMA: 64 rows x 32 cols per wave, K=384; B frags amortized 2x ----
  {
    f32x4 acc[4][2];
    #pragma unroll
    for (int rf = 0; rf < 4; ++rf){
      acc[rf][0] = (f32x4){0.f, 0.f, 0.f, 0.f};
      acc[rf][1] = (f32x4){0.f, 0.f, 0.f, 0.f};
    }
    #pragma unroll 4
    for (int ks = 0; ks < 12; ++ks){
      bf16x8 B0 = __builtin_bit_cast(bf16x8, w1frag[((w * 2 + 0) * 12 + ks) * 64 + lane]);
      bf16x8 B1 = __builtin_bit_cast(bf16x8, w1frag[((w * 2 + 1) * 12 + ks) * 64 + lane]);
      const int koff = ks * 64 + ((lane >> 4) << 4);
      #pragma unroll
      for (int rf = 0; rf < 4; ++rf){
        const int row = rf * 16 + (lane & 15);
        bf16x8 a = __builtin_bit_cast(bf16x8, ldq(wf_raw, 768, row, koff));
        acc[rf][0] = __builtin_amdgcn_mfma_f32_16x16x32_bf16(a, B0, acc[rf][0], 0, 0, 0);
        acc[rf][1] = __builtin_amdgcn_mfma_f32_16x16x32_bf16(a, B1, acc[rf][1], 0, 0, 0);
      }
    }

    float m0 = -3.0e38f, m1 = -3.0e38f;
    #pragma unroll
    for (int rf = 0; rf < 4; ++rf)
      #pragma unroll
      for (int i = 0; i < 4; ++i){
        m0 = fmaxf(m0, acc[rf][0][i]);
        m1 = fmaxf(m1, acc[rf][1][i]);
      }
    m0 = fmaxf(m0, __shfl_xor(m0, 16, 64));
    m0 = fmaxf(m0, __shfl_xor(m0, 32, 64));
    m1 = fmaxf(m1, __shfl_xor(m1, 16, 64));
    m1 = fmaxf(m1, __shfl_xor(m1, 32, 64));
    if (lane < 16){
      atomicMax(pooled + b * NH + w * 32 + lane,      enc_f32(m0));
      atomicMax(pooled + b * NH + w * 32 + 16 + lane, enc_f32(m1));
    }
  }
}

// ---- final: h=tanh(pooled+b1) -> MFMA h@W2 -> tanh -> cosine(v1,v2) ----
__global__ __launch_bounds__(256) void tbcnn_final(
    const unsigned* __restrict__ pooled, const float* __restrict__ b1,
    const uint4* __restrict__ w2frag, const float* __restrict__ b2,
    float* __restrict__ out)
{
  __shared__ __align__(16) unsigned char hls[NB * 256];   // 32 x 128 bf16, swizzled
  __shared__ float os[NB * NH];
  const int t = threadIdx.x;
  const int lane = t & 63;
  const int w = t >> 6;

  {
    const int row = t >> 3;          // batch
    const int q = t & 7;
    const int d0 = q * 16;
    const unsigned* pp = pooled + row * NH + d0;
    const float* bp = b1 + d0;
    float hv[16];
    #pragma unroll
    for (int j = 0; j < 16; ++j) hv[j] = tanhf(dec_f32(pp[j]) + bp[j]);
    st8(hls, 256, row, 2 * d0, hv);
    st8(hls, 256, row, 2 * (d0 + 8), hv + 8);
  }
  __syncthreads();
  {
    f32x4 acc[2][2];
    #pragma unroll
    for (int rf = 0; rf < 2; ++rf){
      acc[rf][0] = (f32x4){0.f,0.f,0.f,0.f};
      acc[rf][1] = (f32x4){0.f,0.f,0.f,0.f};
    }
    #pragma unroll
    for (int ks = 0; ks < 4; ++ks){
      bf16x8 B0 = __builtin_bit_cast(bf16x8, w2frag[((w * 2 + 0) * 4 + ks) * 64 + lane]);
      bf16x8 B1 = __builtin_bit_cast(bf16x8, w2frag[((w * 2 + 1) * 4 + ks) * 64 + lane]);
      const int koff = ks * 64 + ((lane >> 4) << 4);
      #pragma unroll
      for (int rf = 0; rf < 2; ++rf){
        bf16x8 a = __builtin_bit_cast(bf16x8, ldq(hls, 256, rf * 16 + (lane & 15), koff));
        acc[rf][0] = __builtin_amdgcn_mfma_f32_16x16x32_bf16(a, B0, acc[rf][0], 0, 0, 0);
        acc[rf][1] = __builtin_amdgcn_mfma_f32_16x16x32_bf16(a, B1, acc[rf][1], 0, 0, 0);
      }
    }
    #pragma unroll
    for (int rf = 0; rf < 2; ++rf)
      #pragma unroll
      for (int cf = 0; cf < 2; ++cf){
        const int col = w * 32 + cf * 16 + (lane & 15);
        const float bias = b2[col];
        #pragma unroll
        for (int i = 0; i < 4; ++i){
          const int r = rf * 16 + (lane >> 4) * 4 + i;
          os[r * NH + col] = tanhf(acc[rf][cf][i] + bias);
        }
      }
  }
  __syncthreads();
  if (t < 16){
    float s12 = 0.f, s11 = 0.f, s22 = 0.f;
    #pragma unroll 4
    for (int d = 0; d < NH; ++d){
      float a = os[t * NH + d];
      float c = os[(t + 16) * NH + d];
      s12 += a * c; s11 += a * a; s22 += c * c;
    }
    float n1 = fmaxf(sqrtf(s11), 1e-8f);
    float n2 = fmaxf(sqrtf(s22), 1e-8f);
    out[t] = s12 / (n1 * n2);
  }
}

extern "C" void kernel_launch(void* const* d_in, const int* in_sizes, int n_in,
                              void* d_out, int out_size, void* d_ws, size_t ws_size,
                              hipStream_t stream)
{
  const int*   children = (const int*)d_in[0];
  const float* nodeEmb  = (const float*)d_in[1];
  const float* W1       = (const float*)d_in[2];
  const float* b1       = (const float*)d_in[3];
  const float* W2       = (const float*)d_in[4];
  const float* b2       = (const float*)d_in[5];
  float* out = (float*)d_out;

  unsigned* pooled      = (unsigned*)((char*)d_ws + OFF_POOLED);
  uint4* w1frag         = (uint4*)((char*)d_ws + OFF_W1);
  uint4* w2frag         = (uint4*)((char*)d_ws + OFF_W2);
  unsigned char* embF8  = (unsigned char*)((char*)d_ws + OFF_EMB);

  const bool f8 = (ws_size >= WS_NEED_F8);

  tbcnn_prep<<<2080, 256, 0, stream>>>(nodeEmb, W1, W2, pooled, w1frag, w2frag, embF8, f8 ? 1 : 0);
  if (f8)
    tbcnn_main<true><<<NBLK, 256, 0, stream>>>(children, nodeEmb, embF8, w1frag, pooled);
  else
    tbcnn_main<false><<<NBLK, 256, 0, stream>>>(children, nodeEmb, embF8, w1frag, pooled);
  tbcnn_final<<<1, 256, 0, stream>>>(pooled, b1, w2frag, b2, out);
}